// Round 7
// baseline (139.773 us; speedup 1.0000x reference)
//
#include <hip/hip_runtime.h>
#include <math.h>

// MLSWAT neuron forward, T=4 steps.
// Shapes: input [4, 16, 2048, 768] f32, raw_threshes [4] f32, zero_point [1] f32.
// out[t, s] = spike(v_t[s]) - aux, with v recurrence per spatial site s.
//
// Exactness: per-element path is IEEE f32 add/sub/compare only (bit-exact,
// no FMA hazard). Softplus on the 4 raw thresholds replicates numpy/jax
// logaddexp(x,0) staged rounding via double-precision exp/log1p rounded to f32.
//
// R1: 152.9 us (separate th kernel, normal ld/st).
// R2: NT ld/st, 2 streams/thread at i and i+HALF: 150.1 us.
// R3: fused th-compute + hoisted loads: 150.9 us.
// R4: persistent grid + normal stores: 171.6 us (REGRESS).
// R5: wave-adjacent chunks (2KB runs/plane/wave): 135.9 us (5.93 TB/s).
// R6: extend contiguity to 4KB runs/plane/wave (4 chunks/thread:
//     i, i+64, i+128, i+192) — halves region-switch rate again.

static constexpr int TT = 4;
static constexpr int NSPAT = 16 * 2048 * 768;   // 25,165,824 spatial sites
static constexpr int N4 = NSPAT / 4;            // 6,291,456 float4 sites
static constexpr int THREADS = 256;
static constexpr int CH = 4;                    // chunks per thread
static constexpr int PER_BLOCK = THREADS * CH;  // 1024 float4 per plane per block
static constexpr int BLOCKS = N4 / PER_BLOCK;   // 6144, exact (no tail)

typedef float f32x4 __attribute__((ext_vector_type(4)));

__device__ __forceinline__ float step1(float& v, float x, float aux,
                                       float th0, float th1, float th2,
                                       float th3) {
    v = (v + x) + aux;   // left-associated like the reference
    float s = (v >= th0) ? th0
            : (v >= th1) ? th1
            : (v >= th2) ? th2
            : (v >= th3) ? th3
            : 0.0f;
    v = v - s;           // soft reset
    return s - aux;
}

__global__ __launch_bounds__(256) void mlswat_fused_kernel(
        const float* __restrict__ x,
        const float* __restrict__ raw,
        const float* __restrict__ zp,
        float* __restrict__ out) {
    __shared__ float sh[5];
    if (threadIdx.x == 0) {
        float inc[4];
#pragma unroll
        for (int j = 0; j < 4; ++j) {
            float r = raw[j];
            // softplus(r) = max(r,0) + log1p(exp(-|r|)), f32-rounded per stage
            float a = -fabsf(r);
            float e = (float)exp((double)a);     // correctly-rounded f32 exp
            float l = (float)log1p((double)e);   // correctly-rounded f32 log1p
            inc[j] = fmaxf(r, 0.0f) + l;
        }
        float c0 = inc[0];
        float c1 = c0 + inc[1];
        float c2 = c1 + inc[2];
        float c3 = c2 + inc[3];
        sh[0] = c3;   // descending thresholds
        sh[1] = c2;
        sh[2] = c1;
        sh[3] = c0;
        sh[4] = zp[0] / 4.0f;   // aux = zero_point / T (exact: /2^2)
    }
    __syncthreads();
    const float th0 = sh[0], th1 = sh[1], th2 = sh[2], th3 = sh[3];
    const float aux = sh[4];

    const f32x4* __restrict__ xin = (const f32x4*)x;
    f32x4* __restrict__ o = (f32x4*)out;

    // Wave w owns a contiguous 4KB run per plane: float4 range
    // [blk*1024 + w*256, +256). Lane handles 4 chunks at +0,+64,+128,+192.
    const int wave = threadIdx.x >> 6;
    const int lane = threadIdx.x & 63;
    const int i0 = blockIdx.x * PER_BLOCK + wave * (64 * CH) + lane;

    // Hoist all 16 loads (NT: zero-reuse streams).
    f32x4 xv[TT][CH];
#pragma unroll
    for (int t = 0; t < TT; ++t) {
        const size_t b = (size_t)t * N4;
#pragma unroll
        for (int c = 0; c < CH; ++c) {
            xv[t][c] = __builtin_nontemporal_load(&xin[b + i0 + c * 64]);
        }
    }

    f32x4 v[CH];
#pragma unroll
    for (int c = 0; c < CH; ++c) v[c] = {0.5f, 0.5f, 0.5f, 0.5f};  // INITIAL_MEM

#pragma unroll
    for (int t = 0; t < TT; ++t) {
        const size_t b = (size_t)t * N4;
#pragma unroll
        for (int c = 0; c < CH; ++c) {
            f32x4 r;
#pragma unroll
            for (int k = 0; k < 4; ++k) {
                float vv = v[c][k];
                r[k] = step1(vv, xv[t][c][k], aux, th0, th1, th2, th3);
                v[c][k] = vv;
            }
            __builtin_nontemporal_store(r, &o[b + i0 + c * 64]);
        }
    }
}

extern "C" void kernel_launch(void* const* d_in, const int* in_sizes, int n_in,
                              void* d_out, int out_size, void* d_ws, size_t ws_size,
                              hipStream_t stream) {
    const float* x   = (const float*)d_in[0];   // [4,16,2048,768] f32
    const float* raw = (const float*)d_in[1];   // [4] f32
    const float* zp  = (const float*)d_in[2];   // [1] f32
    float* out = (float*)d_out;

    mlswat_fused_kernel<<<BLOCKS, THREADS, 0, stream>>>(x, raw, zp, out);
}

// Round 8
// 135.776 us; speedup vs baseline: 1.0294x; 1.0294x over previous
//
#include <hip/hip_runtime.h>
#include <math.h>

// MLSWAT neuron forward, T=4 steps.
// Shapes: input [4, 16, 2048, 768] f32, raw_threshes [4] f32, zero_point [1] f32.
// out[t, s] = spike(v_t[s]) - aux, with v recurrence per spatial site s.
//
// Exactness: per-element path is IEEE f32 add/sub/compare only (bit-exact,
// no FMA hazard). Softplus on the 4 raw thresholds replicates numpy/jax
// logaddexp(x,0) staged rounding via double-precision exp/log1p rounded to f32.
//
// R1: 152.9 us (separate th kernel, normal ld/st).
// R2: NT ld/st, 2 streams/thread at i and i+HALF: 150.1 us.
// R3: fused th-compute + hoisted loads: 150.9 us.
// R4: persistent grid + normal stores: 171.6 us (REGRESS: L2 store-allocate).
// R5: wave-adjacent chunks (2KB runs/plane/wave): 135.9 us (5.93 TB/s,
//     94% of the 6.29 TB/s copy ceiling). BEST.
// R6: 4KB runs (4 chunks/thread): 139.8 us (REGRESS: 16 hoisted loads
//     -> ~100+ VGPR -> occupancy loss beats contiguity gain).
// R7: revert to R5 exactly. This is the practical roofline: 805 MB
//     mandatory traffic / 6.29 TB/s copy ceiling = 128 us floor + launch.

static constexpr int TT = 4;
static constexpr int NSPAT = 16 * 2048 * 768;   // 25,165,824 spatial sites
static constexpr int N4 = NSPAT / 4;            // 6,291,456 float4 sites
static constexpr int THREADS = 256;
static constexpr int PER_BLOCK = 512;           // float4 per plane per block
static constexpr int BLOCKS = N4 / PER_BLOCK;   // 12288, exact (no tail)

typedef float f32x4 __attribute__((ext_vector_type(4)));

__device__ __forceinline__ float step1(float& v, float x, float aux,
                                       float th0, float th1, float th2,
                                       float th3) {
    v = (v + x) + aux;   // left-associated like the reference
    float s = (v >= th0) ? th0
            : (v >= th1) ? th1
            : (v >= th2) ? th2
            : (v >= th3) ? th3
            : 0.0f;
    v = v - s;           // soft reset
    return s - aux;
}

__global__ __launch_bounds__(256) void mlswat_fused_kernel(
        const float* __restrict__ x,
        const float* __restrict__ raw,
        const float* __restrict__ zp,
        float* __restrict__ out) {
    __shared__ float sh[5];
    if (threadIdx.x == 0) {
        float inc[4];
#pragma unroll
        for (int j = 0; j < 4; ++j) {
            float r = raw[j];
            // softplus(r) = max(r,0) + log1p(exp(-|r|)), f32-rounded per stage
            float a = -fabsf(r);
            float e = (float)exp((double)a);     // correctly-rounded f32 exp
            float l = (float)log1p((double)e);   // correctly-rounded f32 log1p
            inc[j] = fmaxf(r, 0.0f) + l;
        }
        float c0 = inc[0];
        float c1 = c0 + inc[1];
        float c2 = c1 + inc[2];
        float c3 = c2 + inc[3];
        sh[0] = c3;   // descending thresholds
        sh[1] = c2;
        sh[2] = c1;
        sh[3] = c0;
        sh[4] = zp[0] / 4.0f;   // aux = zero_point / T (exact: /2^2)
    }
    __syncthreads();
    const float th0 = sh[0], th1 = sh[1], th2 = sh[2], th3 = sh[3];
    const float aux = sh[4];

    const f32x4* __restrict__ xin = (const f32x4*)x;
    f32x4* __restrict__ o = (f32x4*)out;

    // Wave w of this block owns float4 range [blk*512 + w*128, +128) per
    // plane; lane handles elements i1 = start + lane and i2 = i1 + 64.
    // Per wave per plane: one contiguous 2KB run (two adjacent 1KB chunks).
    const int wave = threadIdx.x >> 6;
    const int lane = threadIdx.x & 63;
    const int i1 = blockIdx.x * PER_BLOCK + wave * 128 + lane;
    const int i2 = i1 + 64;

    // Hoist all 8 loads (NT: zero-reuse streams).
    f32x4 xa[TT], xb[TT];
#pragma unroll
    for (int t = 0; t < TT; ++t) {
        const size_t b = (size_t)t * N4;
        xa[t] = __builtin_nontemporal_load(&xin[b + i1]);
        xb[t] = __builtin_nontemporal_load(&xin[b + i2]);
    }

    f32x4 va = {0.5f, 0.5f, 0.5f, 0.5f};   // INITIAL_MEM
    f32x4 vb = va;
#pragma unroll
    for (int t = 0; t < TT; ++t) {
        const size_t b = (size_t)t * N4;
        f32x4 ra, rb;
#pragma unroll
        for (int k = 0; k < 4; ++k) {
            float vv = va[k];
            ra[k] = step1(vv, xa[t][k], aux, th0, th1, th2, th3);
            va[k] = vv;
            float vw = vb[k];
            rb[k] = step1(vw, xb[t][k], aux, th0, th1, th2, th3);
            vb[k] = vw;
        }
        __builtin_nontemporal_store(ra, &o[b + i1]);
        __builtin_nontemporal_store(rb, &o[b + i2]);
    }
}

extern "C" void kernel_launch(void* const* d_in, const int* in_sizes, int n_in,
                              void* d_out, int out_size, void* d_ws, size_t ws_size,
                              hipStream_t stream) {
    const float* x   = (const float*)d_in[0];   // [4,16,2048,768] f32
    const float* raw = (const float*)d_in[1];   // [4] f32
    const float* zp  = (const float*)d_in[2];   // [1] f32
    float* out = (float*)d_out;

    mlswat_fused_kernel<<<BLOCKS, THREADS, 0, stream>>>(x, raw, zp, out);
}